// Round 13
// baseline (201.815 us; speedup 1.0000x reference)
//
#include <hip/hip_runtime.h>
#include <hip/hip_bf16.h>

#define NB 1024
#define ND 512
#define NM 65536
#define NC 4096
#define CAP 128   // fixed bucket capacity: Poisson(16) => P(any bucket > 128) ~ 1e-80

static constexpr float TEMP = 0.05f;
static constexpr float EPSF = 1e-6f;

typedef __attribute__((ext_vector_type(8))) short short8v;   // 8 bf16 (4 VGPRs)
typedef __attribute__((ext_vector_type(16))) float f32x16;   // MFMA 32x32 accumulator

static __device__ __forceinline__ short f2bf(float f) {
    __hip_bfloat16 h = __float2bfloat16(f);
    return *reinterpret_cast<short*>(&h);
}

// ---------- K1: normalize (wave-per-row) -> bf16; zero cnt+flags; init tgt/denom ----------
__global__ __launch_bounds__(256) void k_norm_init(const float* __restrict__ in,
                                                   const int* __restrict__ indexes,
                                                   const int* __restrict__ labels,
                                                   short* __restrict__ xnb,
                                                   int* __restrict__ tgt,
                                                   float* __restrict__ denom,
                                                   int* __restrict__ cnt,
                                                   int* __restrict__ flags) {
    int wid = threadIdx.x >> 6, l = threadIdx.x & 63;
    int b = blockIdx.x * 4 + wid;
    const float4* row = reinterpret_cast<const float4*>(in + (size_t)b * ND) + l * 2;
    float4 v0 = row[0], v1 = row[1];
    float ss = v0.x * v0.x + v0.y * v0.y + v0.z * v0.z + v0.w * v0.w
             + v1.x * v1.x + v1.y * v1.y + v1.z * v1.z + v1.w * v1.w;
#pragma unroll
    for (int m = 1; m < 64; m <<= 1) ss += __shfl_xor(ss, m);
    float inv = 1.0f / sqrtf(ss);
    short8v o;
    o[0] = f2bf(v0.x * inv); o[1] = f2bf(v0.y * inv);
    o[2] = f2bf(v0.z * inv); o[3] = f2bf(v0.w * inv);
    o[4] = f2bf(v1.x * inv); o[5] = f2bf(v1.y * inv);
    o[6] = f2bf(v1.z * inv); o[7] = f2bf(v1.w * inv);
    *reinterpret_cast<short8v*>(xnb + (size_t)b * ND + l * 8) = o;
    if (threadIdx.x < 16) cnt[blockIdx.x * 16 + threadIdx.x] = 0;   // 256*16 = 4096 = NC
    if (blockIdx.x == 0 && threadIdx.x < 32) flags[threadIdx.x] = 0;
    if (l == 0) {
        tgt[b] = labels[indexes[b]];
        denom[b] = 0.f;
    }
}

// ---------- K2: bucket scatter (builds cnt AND idx; int atomics only) ----------
__global__ __launch_bounds__(256) void k_scatter(const int* __restrict__ labels,
                                                 int* __restrict__ cnt,
                                                 int* __restrict__ idx) {
    int m = blockIdx.x * 256 + threadIdx.x;
    int c = labels[m];
    int pos = atomicAdd(&cnt[c], 1);
    if (pos < CAP) idx[(size_t)c * CAP + pos] = m;
}

// ---------- K3: fused gather ∥ gemm, pipelined via per-col-group ready flags ----------
// Blocks 0..2047: gather 2 clusters each (256 thr = 2 x 128 cols), then leader
//   release-fence + atomicAdd(flag[group]) (group = 128 clusters = 64 blocks).
// Blocks 2048..2303: R7-proven 128x128 MFMA gemm; leader spins flag[bx]==64,
//   acquire-fences, then runs. Deadlock-free under any dispatch order.
__global__ __launch_bounds__(256) void k_gather_gemm(const float* __restrict__ feats,
                                                     const int* __restrict__ idx,
                                                     const int* __restrict__ cnt,
                                                     const short* __restrict__ xnb,
                                                     short* __restrict__ Gb,
                                                     const int* __restrict__ tgt,
                                                     float* __restrict__ denom,
                                                     float* __restrict__ numer,
                                                     int* __restrict__ flags) {
    const int bid = blockIdx.x;
    const int tid = threadIdx.x;

    if (bid < 2048) {
        // ---- gather role: clusters 2*bid + (tid>>7) ----
        int c = bid * 2 + (tid >> 7);
        int col = tid & 127;                 // float4 column 0..127
        int n = cnt[c];
        if (n > CAP) n = CAP;
        const int* bucket = idx + (size_t)c * CAP;
        const float4* F = reinterpret_cast<const float4*>(feats);
        float4 a0 = {0.f, 0.f, 0.f, 0.f}, a1 = {0.f, 0.f, 0.f, 0.f};
        float4 a2 = {0.f, 0.f, 0.f, 0.f}, a3 = {0.f, 0.f, 0.f, 0.f};
        int j = 0;
        for (; j + 3 < n; j += 4) {
            int m0 = bucket[j], m1 = bucket[j + 1];
            int m2 = bucket[j + 2], m3 = bucket[j + 3];
            float4 v0 = F[(size_t)m0 * 128 + col];
            float4 v1 = F[(size_t)m1 * 128 + col];
            float4 v2 = F[(size_t)m2 * 128 + col];
            float4 v3 = F[(size_t)m3 * 128 + col];
            a0.x += v0.x; a0.y += v0.y; a0.z += v0.z; a0.w += v0.w;
            a1.x += v1.x; a1.y += v1.y; a1.z += v1.z; a1.w += v1.w;
            a2.x += v2.x; a2.y += v2.y; a2.z += v2.z; a2.w += v2.w;
            a3.x += v3.x; a3.y += v3.y; a3.z += v3.z; a3.w += v3.w;
        }
        for (; j < n; ++j) {
            int m0 = bucket[j];
            float4 v0 = F[(size_t)m0 * 128 + col];
            a0.x += v0.x; a0.y += v0.y; a0.z += v0.z; a0.w += v0.w;
        }
        short4 o;
        o.x = f2bf(a0.x + a1.x + a2.x + a3.x);
        o.y = f2bf(a0.y + a1.y + a2.y + a3.y);
        o.z = f2bf(a0.z + a1.z + a2.z + a3.z);
        o.w = f2bf(a0.w + a1.w + a2.w + a3.w);
        reinterpret_cast<short4*>(Gb + (size_t)c * ND)[col] = o;
        // publish: all stores drained at barrier, leader release + arrive
        __syncthreads();
        if (tid == 0) {
            __threadfence();
            atomicAdd(&flags[bid >> 6], 1);
        }
        return;
    }

    // ---- gemm role ----
    const int gb = bid - 2048;
    const int bx = gb & 31, by = gb >> 5;
    if (tid == 0) {
        while (atomicAdd(&flags[bx], 0) < 64) __builtin_amdgcn_s_sleep(8);
        __threadfence();                    // acquire before reading Gb
    }
    __syncthreads();

    const int w = tid >> 6;
    const int lane = tid & 63;
    const int ln = lane & 31;
    const int kg = lane >> 5;
    const int row0 = by * 128 + (w >> 1) * 64;  // over B samples
    const int col0 = bx * 128 + (w & 1) * 64;   // over clusters

    f32x16 acc00 = {}, acc01 = {}, acc10 = {}, acc11 = {};
    const short* pa0 = xnb + (size_t)(row0 + ln) * ND + kg * 8;
    const short* pa1 = pa0 + 32 * ND;
    const short* pb0 = Gb + (size_t)(col0 + ln) * ND + kg * 8;
    const short* pb1 = pb0 + 32 * ND;
#pragma unroll 8
    for (int k0 = 0; k0 < ND; k0 += 16) {
        short8v a0 = *reinterpret_cast<const short8v*>(pa0 + k0);
        short8v a1 = *reinterpret_cast<const short8v*>(pa1 + k0);
        short8v b0 = *reinterpret_cast<const short8v*>(pb0 + k0);
        short8v b1 = *reinterpret_cast<const short8v*>(pb1 + k0);
        acc00 = __builtin_amdgcn_mfma_f32_32x32x16_bf16(a0, b0, acc00, 0, 0, 0);
        acc01 = __builtin_amdgcn_mfma_f32_32x32x16_bf16(a0, b1, acc01, 0, 0, 0);
        acc10 = __builtin_amdgcn_mfma_f32_32x32x16_bf16(a1, b0, acc10, 0, 0, 0);
        acc11 = __builtin_amdgcn_mfma_f32_32x32x16_bf16(a1, b1, acc11, 0, 0, 0);
    }
    // C/D layout (m74/m101): col = lane&31, row = (reg&3) + 8*(reg>>2) + 4*(lane>>5)
    int colA = col0 + ln;
    int colB = colA + 32;
    int nA = cnt[colA], nB = cnt[colB];
    float invA = 1.0f / (TEMP * (float)(nA > 0 ? nA : 1));
    float invB = 1.0f / (TEMP * (float)(nB > 0 ? nB : 1));
    float mA = (nA > 0) ? 1.f : 0.f;
    float mB = (nB > 0) ? 1.f : 0.f;
    int rbase = row0 + 4 * kg;
#pragma unroll
    for (int r = 0; r < 16; ++r) {
        int row = rbase + (r & 3) + 8 * (r >> 2);
        int rowH = row + 32;
        float v00 = acc00[r] * invA, v01 = acc01[r] * invB;
        float v10 = acc10[r] * invA, v11 = acc11[r] * invB;
        int t0 = tgt[row], t1 = tgt[rowH];
        if (t0 == colA) numer[row] = v00;
        if (t0 == colB) numer[row] = v01;
        if (t1 == colA) numer[rowH] = v10;
        if (t1 == colB) numer[rowH] = v11;
        float s0 = mA * __expf(v00) + mB * __expf(v01);
        float s1 = mA * __expf(v10) + mB * __expf(v11);
#pragma unroll
        for (int m = 1; m < 32; m <<= 1) {
            s0 += __shfl_xor(s0, m);
            s1 += __shfl_xor(s1, m);
        }
        if (ln == 0) {
            atomicAdd(&denom[row], s0);
            atomicAdd(&denom[rowH], s1);
        }
    }
}

// ---------- K4: final loss (deterministic single-block mean) ----------
__global__ __launch_bounds__(256) void k_final(const float* __restrict__ numer,
                                               const float* __restrict__ denom,
                                               float* __restrict__ out) {
    float s = 0.f;
    for (int i = threadIdx.x; i < NB; i += 256) {
        float p = __expf(numer[i]) / (denom[i] + EPSF);
        s += -logf(p + EPSF);
    }
#pragma unroll
    for (int o = 32; o > 0; o >>= 1) s += __shfl_down(s, o);
    __shared__ float sw[4];
    int lane = threadIdx.x & 63, w = threadIdx.x >> 6;
    if (lane == 0) sw[w] = s;
    __syncthreads();
    if (threadIdx.x == 0) out[0] = (sw[0] + sw[1] + sw[2] + sw[3]) / (float)NB;
}

extern "C" void kernel_launch(void* const* d_in, const int* in_sizes, int n_in,
                              void* d_out, int out_size, void* d_ws, size_t ws_size,
                              hipStream_t stream) {
    const float* inputs   = (const float*)d_in[0];
    const int*   indexes  = (const int*)d_in[1];
    const float* features = (const float*)d_in[2];
    const int*   labels   = (const int*)d_in[3];
    float* out = (float*)d_out;

    // workspace layout (cnt/flags/denom initialized by k_norm_init each call)
    short* Gb     = (short*)d_ws;                    // NC*ND bf16 (4 MB)
    short* xnb    = Gb + (size_t)NC * ND;            // NB*ND bf16 (1 MB)
    float* denom  = (float*)(xnb + (size_t)NB * ND); // NB
    float* numer  = denom + NB;                      // NB
    int*   tgt    = (int*)(numer + NB);              // NB
    int*   flags  = tgt + NB;                        // 32 (+pad)
    int*   cnt    = flags + 64;                      // NC
    int*   idx    = cnt + NC;                        // NC*CAP ints (2 MB)

    k_norm_init<<<NB / 4, 256, 0, stream>>>(inputs, indexes, labels, xnb, tgt, denom, cnt, flags);
    k_scatter<<<NM / 256, 256, 0, stream>>>(labels, cnt, idx);
    k_gather_gemm<<<2048 + 256, 256, 0, stream>>>(features, idx, cnt, xnb, Gb,
                                                  tgt, denom, numer, flags);
    k_final<<<1, 256, 0, stream>>>(numer, denom, out);
}

// Round 14
// 93.846 us; speedup vs baseline: 2.1505x; 2.1505x over previous
//
#include <hip/hip_runtime.h>
#include <hip/hip_bf16.h>

#define NB 1024
#define ND 512
#define NM 65536
#define NC 4096
#define CAP 128   // fixed bucket capacity: Poisson(16) => P(any bucket > 128) ~ 1e-80
#define NSLOT 128 // gemm partial slots per row: 64 col-blocks x 2 waves

static constexpr float TEMP = 0.05f;
static constexpr float EPSF = 1e-6f;

typedef __attribute__((ext_vector_type(8))) short short8v;   // 8 bf16 (4 VGPRs)
typedef __attribute__((ext_vector_type(16))) float f32x16;   // MFMA 32x32 accumulator

static __device__ __forceinline__ short f2bf(float f) {
    __hip_bfloat16 h = __float2bfloat16(f);
    return *reinterpret_cast<short*>(&h);
}

// ---------- K1: normalize (wave-per-row) -> bf16; zero cnt; init tgt ----------
__global__ __launch_bounds__(256) void k_norm_init(const float* __restrict__ in,
                                                   const int* __restrict__ indexes,
                                                   const int* __restrict__ labels,
                                                   short* __restrict__ xnb,
                                                   int* __restrict__ tgt,
                                                   int* __restrict__ cnt) {
    int wid = threadIdx.x >> 6, l = threadIdx.x & 63;
    int b = blockIdx.x * 4 + wid;
    const float4* row = reinterpret_cast<const float4*>(in + (size_t)b * ND) + l * 2;
    float4 v0 = row[0], v1 = row[1];
    float ss = v0.x * v0.x + v0.y * v0.y + v0.z * v0.z + v0.w * v0.w
             + v1.x * v1.x + v1.y * v1.y + v1.z * v1.z + v1.w * v1.w;
#pragma unroll
    for (int m = 1; m < 64; m <<= 1) ss += __shfl_xor(ss, m);
    float inv = 1.0f / sqrtf(ss);
    short8v o;
    o[0] = f2bf(v0.x * inv); o[1] = f2bf(v0.y * inv);
    o[2] = f2bf(v0.z * inv); o[3] = f2bf(v0.w * inv);
    o[4] = f2bf(v1.x * inv); o[5] = f2bf(v1.y * inv);
    o[6] = f2bf(v1.z * inv); o[7] = f2bf(v1.w * inv);
    *reinterpret_cast<short8v*>(xnb + (size_t)b * ND + l * 8) = o;
    if (threadIdx.x < 16) cnt[blockIdx.x * 16 + threadIdx.x] = 0;   // 256*16 = 4096 = NC
    if (l == 0) tgt[b] = labels[indexes[b]];
}

// ---------- K2: bucket scatter (builds cnt AND idx; int atomics only) ----------
__global__ __launch_bounds__(256) void k_scatter(const int* __restrict__ labels,
                                                 int* __restrict__ cnt,
                                                 int* __restrict__ idx) {
    int m = blockIdx.x * 256 + threadIdx.x;
    int c = labels[m];
    int pos = atomicAdd(&cnt[c], 1);
    if (pos < CAP) idx[(size_t)c * CAP + pos] = m;
}

// ---------- K3: gather-sum features into bf16 cluster centroids (R7-proven) ----------
__global__ __launch_bounds__(128) void k_gather(const float* __restrict__ feats,
                                                const int* __restrict__ idx,
                                                const int* __restrict__ cnt,
                                                short* __restrict__ Gb) {
    int c = blockIdx.x;
    int t = threadIdx.x;  // float4 column 0..127
    int n = cnt[c];
    if (n > CAP) n = CAP;
    const int* bucket = idx + (size_t)c * CAP;
    const float4* F = reinterpret_cast<const float4*>(feats);
    float4 a0 = {0.f, 0.f, 0.f, 0.f}, a1 = {0.f, 0.f, 0.f, 0.f};
    float4 a2 = {0.f, 0.f, 0.f, 0.f}, a3 = {0.f, 0.f, 0.f, 0.f};
    int j = 0;
    for (; j + 3 < n; j += 4) {
        int m0 = bucket[j], m1 = bucket[j + 1];
        int m2 = bucket[j + 2], m3 = bucket[j + 3];
        float4 v0 = F[(size_t)m0 * 128 + t];
        float4 v1 = F[(size_t)m1 * 128 + t];
        float4 v2 = F[(size_t)m2 * 128 + t];
        float4 v3 = F[(size_t)m3 * 128 + t];
        a0.x += v0.x; a0.y += v0.y; a0.z += v0.z; a0.w += v0.w;
        a1.x += v1.x; a1.y += v1.y; a1.z += v1.z; a1.w += v1.w;
        a2.x += v2.x; a2.y += v2.y; a2.z += v2.z; a2.w += v2.w;
        a3.x += v3.x; a3.y += v3.y; a3.z += v3.z; a3.w += v3.w;
    }
    for (; j < n; ++j) {
        int m0 = bucket[j];
        float4 v0 = F[(size_t)m0 * 128 + t];
        a0.x += v0.x; a0.y += v0.y; a0.z += v0.z; a0.w += v0.w;
    }
    short4 o;
    o.x = f2bf(a0.x + a1.x + a2.x + a3.x);
    o.y = f2bf(a0.y + a1.y + a2.y + a3.y);
    o.z = f2bf(a0.z + a1.z + a2.z + a3.z);
    o.w = f2bf(a0.w + a1.w + a2.w + a3.w);
    reinterpret_cast<short4*>(Gb + (size_t)c * ND)[t] = o;
}

// ---------- K4: MFMA GEMM 128x64/block (512 blocks = 2/CU, 2 waves/SIMD) ----------
// 4 waves in 2(row)x2(col); each wave 64x32 via two chained-free 32x32 MFMAs.
// Epilogue: per-wave exp-sum partial -> part[slot][row] (no atomics);
//           target logit -> numer[row] (unique writer).
__global__ __launch_bounds__(256) void k_gemm_mfma(const short* __restrict__ A,
                                                   const short* __restrict__ Bm,
                                                   const int* __restrict__ cnt,
                                                   const int* __restrict__ tgt,
                                                   float* __restrict__ part,
                                                   float* __restrict__ numer) {
    const int tid = threadIdx.x;
    const int w = tid >> 6;
    const int lane = tid & 63;
    const int ln = lane & 31;
    const int kg = lane >> 5;
    const int bx = blockIdx.x;                     // 0..63 over clusters
    const int row0 = blockIdx.y * 128 + (w >> 1) * 64;   // over B samples
    const int col0 = bx * 64 + (w & 1) * 32;             // over clusters

    f32x16 acc0 = {}, acc1 = {};
    const short* pa0 = A + (size_t)(row0 + ln) * ND + kg * 8;
    const short* pa1 = pa0 + 32 * ND;
    const short* pb0 = Bm + (size_t)(col0 + ln) * ND + kg * 8;
#pragma unroll 8
    for (int k0 = 0; k0 < ND; k0 += 16) {
        short8v a0 = *reinterpret_cast<const short8v*>(pa0 + k0);
        short8v a1 = *reinterpret_cast<const short8v*>(pa1 + k0);
        short8v b0 = *reinterpret_cast<const short8v*>(pb0 + k0);
        acc0 = __builtin_amdgcn_mfma_f32_32x32x16_bf16(a0, b0, acc0, 0, 0, 0);
        acc1 = __builtin_amdgcn_mfma_f32_32x32x16_bf16(a1, b0, acc1, 0, 0, 0);
    }
    // C/D layout (m74/m101): col = lane&31, row = (reg&3) + 8*(reg>>2) + 4*(lane>>5)
    int col = col0 + ln;
    int n = cnt[col];
    float inv = 1.0f / (TEMP * (float)(n > 0 ? n : 1));
    float mask = (n > 0) ? 1.f : 0.f;
    int slot = bx * 2 + (w & 1);                   // 0..127, unique per (wave,col-half)
    int rbase = row0 + 4 * kg;
#pragma unroll
    for (int r = 0; r < 16; ++r) {
        int row = rbase + (r & 3) + 8 * (r >> 2);
        int rowH = row + 32;
        float v0 = acc0[r] * inv;
        float v1 = acc1[r] * inv;
        if (tgt[row] == col) numer[row] = v0;
        if (tgt[rowH] == col) numer[rowH] = v1;
        float s0 = mask * __expf(v0);
        float s1 = mask * __expf(v1);
#pragma unroll
        for (int m = 1; m < 32; m <<= 1) {
            s0 += __shfl_xor(s0, m);
            s1 += __shfl_xor(s1, m);
        }
        if (ln == 0) {
            part[(size_t)slot * NB + row] = s0;
            part[(size_t)slot * NB + rowH] = s1;
        }
    }
}

// ---------- K5: final loss (sum partials; deterministic single-block mean) ----------
__global__ __launch_bounds__(256) void k_final(const float* __restrict__ part,
                                               const float* __restrict__ numer,
                                               float* __restrict__ out) {
    float s = 0.f;
    for (int row = threadIdx.x; row < NB; row += 256) {
        float d = 0.f;
        for (int sl = 0; sl < NSLOT; ++sl) d += part[(size_t)sl * NB + row];
        float p = __expf(numer[row]) / (d + EPSF);
        s += -logf(p + EPSF);
    }
#pragma unroll
    for (int o = 32; o > 0; o >>= 1) s += __shfl_down(s, o);
    __shared__ float sw[4];
    int lane = threadIdx.x & 63, w = threadIdx.x >> 6;
    if (lane == 0) sw[w] = s;
    __syncthreads();
    if (threadIdx.x == 0) out[0] = (sw[0] + sw[1] + sw[2] + sw[3]) / (float)NB;
}

extern "C" void kernel_launch(void* const* d_in, const int* in_sizes, int n_in,
                              void* d_out, int out_size, void* d_ws, size_t ws_size,
                              hipStream_t stream) {
    const float* inputs   = (const float*)d_in[0];
    const int*   indexes  = (const int*)d_in[1];
    const float* features = (const float*)d_in[2];
    const int*   labels   = (const int*)d_in[3];
    float* out = (float*)d_out;

    // workspace layout (everything written before read each call; no memsets)
    short* Gb     = (short*)d_ws;                    // NC*ND bf16 (4 MB)
    short* xnb    = Gb + (size_t)NC * ND;            // NB*ND bf16 (1 MB)
    float* part   = (float*)(xnb + (size_t)NB * ND); // NSLOT*NB f32 (512 KB)
    float* numer  = part + (size_t)NSLOT * NB;       // NB
    int*   tgt    = (int*)(numer + NB);              // NB
    int*   cnt    = tgt + NB;                        // NC
    int*   idx    = cnt + NC;                        // NC*CAP ints (2 MB)

    k_norm_init<<<NB / 4, 256, 0, stream>>>(inputs, indexes, labels, xnb, tgt, cnt);
    k_scatter<<<NM / 256, 256, 0, stream>>>(labels, cnt, idx);
    k_gather<<<NC, 128, 0, stream>>>(features, idx, cnt, Gb);
    dim3 g(NC / 64, NB / 128);
    k_gemm_mfma<<<g, 256, 0, stream>>>(xnb, Gb, cnt, tgt, part, numer);
    k_final<<<1, 256, 0, stream>>>(part, numer, out);
}

// Round 15
// 71.653 us; speedup vs baseline: 2.8166x; 1.3097x over previous
//
#include <hip/hip_runtime.h>
#include <hip/hip_bf16.h>

#define NB 1024
#define ND 512
#define NM 65536
#define NC 4096
#define CAP 128   // fixed bucket capacity: Poisson(16) => P(any bucket > 128) ~ 1e-80

static constexpr float TEMP = 0.05f;
static constexpr float EPSF = 1e-6f;

typedef __attribute__((ext_vector_type(8))) short short8v;   // 8 bf16 (4 VGPRs)
typedef __attribute__((ext_vector_type(16))) float f32x16;   // MFMA 32x32 accumulator

static __device__ __forceinline__ short f2bf(float f) {
    __hip_bfloat16 h = __float2bfloat16(f);
    return *reinterpret_cast<short*>(&h);
}

// ---------- K1: normalize (wave-per-row) -> bf16; zero cnt; init tgt/denom ----------
__global__ __launch_bounds__(256) void k_norm_init(const float* __restrict__ in,
                                                   const int* __restrict__ indexes,
                                                   const int* __restrict__ labels,
                                                   short* __restrict__ xnb,
                                                   int* __restrict__ tgt,
                                                   float* __restrict__ denom,
                                                   int* __restrict__ cnt) {
    int wid = threadIdx.x >> 6, l = threadIdx.x & 63;
    int b = blockIdx.x * 4 + wid;
    const float4* row = reinterpret_cast<const float4*>(in + (size_t)b * ND) + l * 2;
    float4 v0 = row[0], v1 = row[1];
    float ss = v0.x * v0.x + v0.y * v0.y + v0.z * v0.z + v0.w * v0.w
             + v1.x * v1.x + v1.y * v1.y + v1.z * v1.z + v1.w * v1.w;
#pragma unroll
    for (int m = 1; m < 64; m <<= 1) ss += __shfl_xor(ss, m);
    float inv = 1.0f / sqrtf(ss);
    short8v o;
    o[0] = f2bf(v0.x * inv); o[1] = f2bf(v0.y * inv);
    o[2] = f2bf(v0.z * inv); o[3] = f2bf(v0.w * inv);
    o[4] = f2bf(v1.x * inv); o[5] = f2bf(v1.y * inv);
    o[6] = f2bf(v1.z * inv); o[7] = f2bf(v1.w * inv);
    *reinterpret_cast<short8v*>(xnb + (size_t)b * ND + l * 8) = o;
    if (threadIdx.x < 16) cnt[blockIdx.x * 16 + threadIdx.x] = 0;   // 256*16 = 4096 = NC
    if (l == 0) {
        tgt[b] = labels[indexes[b]];
        denom[b] = 0.f;
    }
}

// ---------- K2: bucket scatter (builds cnt AND idx; int atomics only) ----------
__global__ __launch_bounds__(256) void k_scatter(const int* __restrict__ labels,
                                                 int* __restrict__ cnt,
                                                 int* __restrict__ idx) {
    int m = blockIdx.x * 256 + threadIdx.x;
    int c = labels[m];
    int pos = atomicAdd(&cnt[c], 1);
    if (pos < CAP) idx[(size_t)c * CAP + pos] = m;
}

// ---------- K3: gather-sum features into bf16 cluster centroids (R7-proven) ----------
__global__ __launch_bounds__(128) void k_gather(const float* __restrict__ feats,
                                                const int* __restrict__ idx,
                                                const int* __restrict__ cnt,
                                                short* __restrict__ Gb) {
    int c = blockIdx.x;
    int t = threadIdx.x;  // float4 column 0..127
    int n = cnt[c];
    if (n > CAP) n = CAP;
    const int* bucket = idx + (size_t)c * CAP;
    const float4* F = reinterpret_cast<const float4*>(feats);
    float4 a0 = {0.f, 0.f, 0.f, 0.f}, a1 = {0.f, 0.f, 0.f, 0.f};
    float4 a2 = {0.f, 0.f, 0.f, 0.f}, a3 = {0.f, 0.f, 0.f, 0.f};
    int j = 0;
    for (; j + 3 < n; j += 4) {
        int m0 = bucket[j], m1 = bucket[j + 1];
        int m2 = bucket[j + 2], m3 = bucket[j + 3];
        float4 v0 = F[(size_t)m0 * 128 + t];
        float4 v1 = F[(size_t)m1 * 128 + t];
        float4 v2 = F[(size_t)m2 * 128 + t];
        float4 v3 = F[(size_t)m3 * 128 + t];
        a0.x += v0.x; a0.y += v0.y; a0.z += v0.z; a0.w += v0.w;
        a1.x += v1.x; a1.y += v1.y; a1.z += v1.z; a1.w += v1.w;
        a2.x += v2.x; a2.y += v2.y; a2.z += v2.z; a2.w += v2.w;
        a3.x += v3.x; a3.y += v3.y; a3.z += v3.z; a3.w += v3.w;
    }
    for (; j < n; ++j) {
        int m0 = bucket[j];
        float4 v0 = F[(size_t)m0 * 128 + t];
        a0.x += v0.x; a0.y += v0.y; a0.z += v0.z; a0.w += v0.w;
    }
    short4 o;
    o.x = f2bf(a0.x + a1.x + a2.x + a3.x);
    o.y = f2bf(a0.y + a1.y + a2.y + a3.y);
    o.z = f2bf(a0.z + a1.z + a2.z + a3.z);
    o.w = f2bf(a0.w + a1.w + a2.w + a3.w);
    reinterpret_cast<short4*>(Gb + (size_t)c * ND)[t] = o;
}

// ---------- K4: MFMA GEMM (R7 tile/grid) + explicit 4-stage prefetch pipeline ----------
// 128x128 block tile, 4 waves (2x2), wave = 64x64 via 2x2 v_mfma_f32_32x32x16_bf16.
// Named stage registers force ~12-16 loads in flight to hide L3 latency at 1 wave/SIMD.
__global__ __launch_bounds__(256, 1) void k_gemm_mfma(const short* __restrict__ A,
                                                      const short* __restrict__ Bm,
                                                      const int* __restrict__ cnt,
                                                      const int* __restrict__ tgt,
                                                      float* __restrict__ denom,
                                                      float* __restrict__ numer) {
    const int tid = threadIdx.x;
    const int w = tid >> 6;
    const int lane = tid & 63;
    const int ln = lane & 31;
    const int kg = lane >> 5;
    const int row0 = blockIdx.y * 128 + (w >> 1) * 64;  // over B samples
    const int col0 = blockIdx.x * 128 + (w & 1) * 64;   // over clusters

    f32x16 acc00 = {}, acc01 = {}, acc10 = {}, acc11 = {};
    const short* pa0 = A + (size_t)(row0 + ln) * ND + kg * 8;
    const short* pa1 = pa0 + 32 * ND;
    const short* pb0 = Bm + (size_t)(col0 + ln) * ND + kg * 8;
    const short* pb1 = pb0 + 32 * ND;

    short8v a0_0, a1_0, b0_0, b1_0;
    short8v a0_1, a1_1, b0_1, b1_1;
    short8v a0_2, a1_2, b0_2, b1_2;
    short8v a0_3, a1_3, b0_3, b1_3;

#define LD(S, K)                                                      \
    a0_##S = *reinterpret_cast<const short8v*>(pa0 + (K));            \
    a1_##S = *reinterpret_cast<const short8v*>(pa1 + (K));            \
    b0_##S = *reinterpret_cast<const short8v*>(pb0 + (K));            \
    b1_##S = *reinterpret_cast<const short8v*>(pb1 + (K));
#define MM(S)                                                                     \
    acc00 = __builtin_amdgcn_mfma_f32_32x32x16_bf16(a0_##S, b0_##S, acc00, 0, 0, 0); \
    acc01 = __builtin_amdgcn_mfma_f32_32x32x16_bf16(a0_##S, b1_##S, acc01, 0, 0, 0); \
    acc10 = __builtin_amdgcn_mfma_f32_32x32x16_bf16(a1_##S, b0_##S, acc10, 0, 0, 0); \
    acc11 = __builtin_amdgcn_mfma_f32_32x32x16_bf16(a1_##S, b1_##S, acc11, 0, 0, 0);

    LD(0, 0) LD(1, 16) LD(2, 32) LD(3, 48)
#pragma unroll
    for (int k0 = 0; k0 < ND; k0 += 64) {
        MM(0) if (k0 + 64 < ND) { LD(0, k0 + 64) }
        MM(1) if (k0 + 80 < ND) { LD(1, k0 + 80) }
        MM(2) if (k0 + 96 < ND) { LD(2, k0 + 96) }
        MM(3) if (k0 + 112 < ND) { LD(3, k0 + 112) }
    }
#undef LD
#undef MM

    // C/D layout (m74/m101): col = lane&31, row = (reg&3) + 8*(reg>>2) + 4*(lane>>5)
    int colA = col0 + ln;
    int colB = colA + 32;
    int nA = cnt[colA], nB = cnt[colB];
    float invA = 1.0f / (TEMP * (float)(nA > 0 ? nA : 1));
    float invB = 1.0f / (TEMP * (float)(nB > 0 ? nB : 1));
    float mA = (nA > 0) ? 1.f : 0.f;
    float mB = (nB > 0) ? 1.f : 0.f;
    int rbase = row0 + 4 * kg;
#pragma unroll
    for (int r = 0; r < 16; ++r) {
        int row = rbase + (r & 3) + 8 * (r >> 2);
        int rowH = row + 32;
        float v00 = acc00[r] * invA, v01 = acc01[r] * invB;
        float v10 = acc10[r] * invA, v11 = acc11[r] * invB;
        int t0 = tgt[row], t1 = tgt[rowH];
        if (t0 == colA) numer[row] = v00;
        if (t0 == colB) numer[row] = v01;
        if (t1 == colA) numer[rowH] = v10;
        if (t1 == colB) numer[rowH] = v11;
        float s0 = mA * __expf(v00) + mB * __expf(v01);
        float s1 = mA * __expf(v10) + mB * __expf(v11);
#pragma unroll
        for (int m = 1; m < 32; m <<= 1) {
            s0 += __shfl_xor(s0, m);
            s1 += __shfl_xor(s1, m);
        }
        if (ln == 0) {
            atomicAdd(&denom[row], s0);
            atomicAdd(&denom[rowH], s1);
        }
    }
}

// ---------- K5: final loss (deterministic single-block mean) ----------
__global__ __launch_bounds__(256) void k_final(const float* __restrict__ numer,
                                               const float* __restrict__ denom,
                                               float* __restrict__ out) {
    float s = 0.f;
    for (int i = threadIdx.x; i < NB; i += 256) {
        float p = __expf(numer[i]) / (denom[i] + EPSF);
        s += -logf(p + EPSF);
    }
#pragma unroll
    for (int o = 32; o > 0; o >>= 1) s += __shfl_down(s, o);
    __shared__ float sw[4];
    int lane = threadIdx.x & 63, w = threadIdx.x >> 6;
    if (lane == 0) sw[w] = s;
    __syncthreads();
    if (threadIdx.x == 0) out[0] = (sw[0] + sw[1] + sw[2] + sw[3]) / (float)NB;
}

extern "C" void kernel_launch(void* const* d_in, const int* in_sizes, int n_in,
                              void* d_out, int out_size, void* d_ws, size_t ws_size,
                              hipStream_t stream) {
    const float* inputs   = (const float*)d_in[0];
    const int*   indexes  = (const int*)d_in[1];
    const float* features = (const float*)d_in[2];
    const int*   labels   = (const int*)d_in[3];
    float* out = (float*)d_out;

    // workspace layout (everything written before read each call; no memsets)
    short* Gb     = (short*)d_ws;                    // NC*ND bf16 (4 MB)
    short* xnb    = Gb + (size_t)NC * ND;            // NB*ND bf16 (1 MB)
    float* denom  = (float*)(xnb + (size_t)NB * ND); // NB
    float* numer  = denom + NB;                      // NB
    int*   tgt    = (int*)(numer + NB);              // NB
    int*   cnt    = tgt + NB;                        // NC
    int*   idx    = cnt + NC;                        // NC*CAP ints (2 MB)

    k_norm_init<<<NB / 4, 256, 0, stream>>>(inputs, indexes, labels, xnb, tgt, denom, cnt);
    k_scatter<<<NM / 256, 256, 0, stream>>>(labels, cnt, idx);
    k_gather<<<NC, 128, 0, stream>>>(features, idx, cnt, Gb);
    dim3 g(NC / 128, NB / 128);
    k_gemm_mfma<<<g, 256, 0, stream>>>(xnb, Gb, cnt, tgt, denom, numer);
    k_final<<<1, 256, 0, stream>>>(numer, denom, out);
}